// Round 1
// baseline (883.646 us; speedup 1.0000x reference)
//
#include <hip/hip_runtime.h>
#include <stdint.h>
#include <stddef.h>

typedef unsigned short u16;
using bf16x8 = __attribute__((ext_vector_type(8))) short;
using f32x4  = __attribute__((ext_vector_type(4))) float;

__device__ __forceinline__ float bf2f(short h) {
  uint32_t u = ((uint32_t)(u16)h) << 16;
  return __builtin_bit_cast(float, u);
}
__device__ __forceinline__ short f2bf(float f) {
  uint32_t u = __builtin_bit_cast(uint32_t, f);
  u += 0x7FFFu + ((u >> 16) & 1u);   // RNE
  return (short)(u >> 16);
}

// ---------------------------------------------------------------- convert ---
struct ConvArgs {
  const float* src[8];
  u16* dst[8];
  int start4[9];   // exclusive prefix in float4 units
};

__global__ __launch_bounds__(256) void convert_all(ConvArgs a) {
  int idx = blockIdx.x * 256 + threadIdx.x;
  if (idx >= a.start4[8]) return;
  int s = 0;
#pragma unroll
  for (int i = 1; i < 8; ++i) s += (idx >= a.start4[i]) ? 1 : 0;
  int off = idx - a.start4[s];
  const float4* sp = (const float4*)a.src[s];
  float4 v = sp[off];
  ushort4 o;
  o.x = (u16)f2bf(v.x); o.y = (u16)f2bf(v.y);
  o.z = (u16)f2bf(v.z); o.w = (u16)f2bf(v.w);
  *(ushort4*)(a.dst[s] + (size_t)off * 4) = o;
}

// ------------------------------------------------------------------- GEMM ---
// C[M,N] = A[M,K1] @ B[N,K1]^T (+ A2@B2^T if DUAL) + bias, optional relu.
// A,B row-major bf16 (K contiguous). M must be multiple of 128; N guarded.
// BIAS: 0 none, 1 per-col (bias[n]), 2 per-row (bias[m]).
template<int BIAS, bool RELU, bool OUTBF16, bool DUAL>
__global__ __launch_bounds__(256) void gemm_nt(
    const u16* __restrict__ A, int lda,
    const u16* __restrict__ B, int ldb,
    const u16* __restrict__ A2, int lda2,
    const u16* __restrict__ B2, int ldb2,
    int K1, int K2,
    const float* __restrict__ bias,
    void* __restrict__ C, int ldc, int N)
{
  __shared__ u16 As[128 * 40];   // stride 40 (pad +8): 2-way bank alias = free
  __shared__ u16 Bs[128 * 40];

  const int tid  = threadIdx.x;
  const int m0   = blockIdx.y * 128;
  const int n0   = blockIdx.x * 128;
  const int wave = tid >> 6, lane = tid & 63;
  const int lrow = lane & 15, quad = lane >> 4;
  const int wm   = (wave & 1) * 64, wn = (wave >> 1) * 64;

  f32x4 zero = {0.f, 0.f, 0.f, 0.f};
  f32x4 acc[4][4];
#pragma unroll
  for (int i = 0; i < 4; ++i)
#pragma unroll
    for (int j = 0; j < 4; ++j) acc[i][j] = zero;

  const int KK = DUAL ? (K1 + K2) : K1;
  for (int k0 = 0; k0 < KK; k0 += 32) {
    const u16* Ap; const u16* Bp; int la, lb, kk;
    if (!DUAL || k0 < K1) { Ap = A;  Bp = B;  la = lda;  lb = ldb;  kk = k0; }
    else                  { Ap = A2; Bp = B2; la = lda2; lb = ldb2; kk = k0 - K1; }

#pragma unroll
    for (int i = 0; i < 2; ++i) {
      int idx = tid + i * 256;            // 0..511
      int row = idx >> 2, c = idx & 3;    // 4 x 16B chunks per 32-elem row
      uint4 av = *(const uint4*)(Ap + (size_t)(m0 + row) * la + kk + c * 8);
      *(uint4*)(&As[row * 40 + c * 8]) = av;
      int brow = n0 + row;
      uint4 bv = make_uint4(0u, 0u, 0u, 0u);
      if (brow < N) bv = *(const uint4*)(Bp + (size_t)brow * lb + kk + c * 8);
      *(uint4*)(&Bs[row * 40 + c * 8]) = bv;
    }
    __syncthreads();

    bf16x8 af[4], bfr[4];
#pragma unroll
    for (int i = 0; i < 4; ++i)
      af[i] = *(const bf16x8*)(&As[(wm + i * 16 + lrow) * 40 + quad * 8]);
#pragma unroll
    for (int j = 0; j < 4; ++j)
      bfr[j] = *(const bf16x8*)(&Bs[(wn + j * 16 + lrow) * 40 + quad * 8]);
#pragma unroll
    for (int i = 0; i < 4; ++i)
#pragma unroll
      for (int j = 0; j < 4; ++j)
        acc[i][j] = __builtin_amdgcn_mfma_f32_16x16x32_bf16(af[i], bfr[j], acc[i][j], 0, 0, 0);
    __syncthreads();
  }

  // epilogue: C layout col=lane&15, row=quad*4+r (m89/m91-verified)
#pragma unroll
  for (int i = 0; i < 4; ++i) {
#pragma unroll
    for (int j = 0; j < 4; ++j) {
      int gn = n0 + wn + j * 16 + lrow;
      if (gn >= N) continue;
      float bc = (BIAS == 1) ? bias[gn] : 0.0f;
#pragma unroll
      for (int r = 0; r < 4; ++r) {
        int gm = m0 + wm + i * 16 + quad * 4 + r;
        float v = acc[i][j][r] + bc;
        if (BIAS == 2) v += bias[gm];
        if (RELU) v = fmaxf(v, 0.0f);
        if (OUTBF16) ((u16*)C)[(size_t)gm * ldc + gn] = (u16)f2bf(v);
        else         ((float*)C)[(size_t)gm * ldc + gn] = v;
      }
    }
  }
}

// ------------------------------------------------- fused attention+sparsemax
// One block per (head, 16-query tile). 512 threads = 8 waves.
// Scores S[16][4096] bf16 in LDS; Newton root-find for tau; P@V via MFMA.
__global__ __launch_bounds__(512) void attn_sparsemax(
    const u16* __restrict__ Q,    // [2048][1024] bf16
    const u16* __restrict__ Km,   // [4096][1024] bf16
    const u16* __restrict__ Vt,   // [1024][4096] bf16 (V transposed)
    u16* __restrict__ AO)         // [2048][1024] bf16
{
  constexpr int SROW = 4096 + 8;          // +8 pad: row bank shift 4 -> 2-way (free)
  __shared__ u16 S[16 * SROW];            // 131328 B
  __shared__ float Ored[2][4][256];       // cross-wave O reduction, 8 KB
  __shared__ float tauS[16];

  const int id    = blockIdx.x;
  const int head  = (id & 7) * 2 + ((id >> 3) >> 7);  // XCD-affine: 2 heads/XCD
  const int qblk  = (id >> 3) & 127;
  const int qbase = qblk * 16;
  const int tid   = threadIdx.x;
  const int wave  = tid >> 6, lane = tid & 63;
  const int lrow  = lane & 15, quad = lane >> 4;

  // Q fragments (A-operand: m=lane&15, k=quad*8+j), two k-chunks cover dh=64
  const u16* qp = Q + (size_t)(qbase + lrow) * 1024 + head * 64 + quad * 8;
  bf16x8 qf0 = *(const bf16x8*)qp;
  bf16x8 qf1 = *(const bf16x8*)(qp + 32);

  // ---- scores: wave w owns keys [w*512, w*512+512) --------------------------
  const float scale = 1.0f / 32.0f;       // 1/sqrt(1024)
  for (int kt = 0; kt < 32; ++kt) {
    int key0 = wave * 512 + kt * 16;
    const u16* kp = Km + (size_t)(key0 + lrow) * 1024 + head * 64 + quad * 8;
    bf16x8 kf0 = *(const bf16x8*)kp;
    bf16x8 kf1 = *(const bf16x8*)(kp + 32);
    f32x4 c = {0.f, 0.f, 0.f, 0.f};
    c = __builtin_amdgcn_mfma_f32_16x16x32_bf16(qf0, kf0, c, 0, 0, 0);
    c = __builtin_amdgcn_mfma_f32_16x16x32_bf16(qf1, kf1, c, 0, 0, 0);
#pragma unroll
    for (int r = 0; r < 4; ++r)
      S[(quad * 4 + r) * SROW + key0 + lrow] = (u16)f2bf(c[r] * scale);
  }
  __syncthreads();

  // ---- sparsemax tau via Newton on f(tau)=sum(max(z-tau,0))-1 ---------------
  // wave w owns rows 2w, 2w+1; 64 elems/lane register-resident.
#pragma unroll 1
  for (int rr = 0; rr < 2; ++rr) {
    int row = wave * 2 + rr;
    float z[64];
#pragma unroll
    for (int t = 0; t < 8; ++t) {
      bf16x8 v = *(const bf16x8*)(&S[row * SROW + t * 512 + lane * 8]);
#pragma unroll
      for (int j = 0; j < 8; ++j) z[t * 8 + j] = bf2f(v[j]);
    }
    float s = 0.f;
#pragma unroll
    for (int j = 0; j < 64; ++j) s += z[j];
#pragma unroll
    for (int o = 32; o; o >>= 1) s += __shfl_xor(s, o, 64);
    float tau = (s - 1.0f) * (1.0f / 4096.0f);   // start below root -> monotone up
    for (int it = 0; it < 32; ++it) {
      float ls = 0.f, lc = 0.f;
#pragma unroll
      for (int j = 0; j < 64; ++j) {
        if (z[j] > tau) { ls += z[j]; lc += 1.0f; }
      }
#pragma unroll
      for (int o = 32; o; o >>= 1) {
        ls += __shfl_xor(ls, o, 64);
        lc += __shfl_xor(lc, o, 64);
      }
      if (lc < 0.5f) break;                      // degenerate guard
      float nt = (ls - 1.0f) / lc;
      if (nt == tau) break;                      // support stable -> exact root
      tau = nt;
    }
    if (lane == 0) tauS[row] = tau;
  }
  __syncthreads();

  // ---- P = max(z - tau, 0) in place -----------------------------------------
#pragma unroll 2
  for (int i = 0; i < 16; ++i) {
    int cidx = tid + i * 512;          // 8192 chunks of 8
    int row  = cidx >> 9;
    int off  = (cidx & 511) * 8;
    float tau = tauS[row];
    u16* p = &S[row * SROW + off];
    bf16x8 v = *(const bf16x8*)p;
    bf16x8 o;
#pragma unroll
    for (int j = 0; j < 8; ++j) {
      float f = fmaxf(bf2f(v[j]) - tau, 0.0f);
      o[j] = f2bf(f);
    }
    *(bf16x8*)p = o;
  }
  __syncthreads();

  // ---- O = P @ V: waves split (dh-group x key-half) -------------------------
  const int dhg = wave & 3, kh = wave >> 2;
  f32x4 oacc = {0.f, 0.f, 0.f, 0.f};
  const u16* vrow = Vt + (size_t)(head * 64 + dhg * 16 + lrow) * 4096 + kh * 2048 + quad * 8;
  const u16* prow = &S[lrow * SROW + kh * 2048 + quad * 8];
  for (int kt = 0; kt < 64; ++kt) {
    bf16x8 pf = *(const bf16x8*)(prow + kt * 32);
    bf16x8 vf = *(const bf16x8*)(vrow + kt * 32);
    oacc = __builtin_amdgcn_mfma_f32_16x16x32_bf16(pf, vf, oacc, 0, 0, 0);
  }
  float* orp = &Ored[kh][dhg][0];
#pragma unroll
  for (int r = 0; r < 4; ++r) orp[(quad * 4 + r) * 16 + lrow] = oacc[r];
  __syncthreads();
  if (kh == 0) {
    const float* other = &Ored[1][dhg][0];
#pragma unroll
    for (int r = 0; r < 4; ++r) {
      float v = oacc[r] + other[(quad * 4 + r) * 16 + lrow];
      AO[(size_t)(qbase + quad * 4 + r) * 1024 + head * 64 + dhg * 16 + lrow] = (u16)f2bf(v);
    }
  }
}

// ---------------------------------------------------------------- launcher --
extern "C" void kernel_launch(void* const* d_in, const int* in_sizes, int n_in,
                              void* d_out, int out_size, void* d_ws, size_t ws_size,
                              hipStream_t stream) {
  const float* enc = (const float*)d_in[0];
  const float* mem = (const float*)d_in[1];
  const float* Wq  = (const float*)d_in[2];
  const float* bq  = (const float*)d_in[3];
  const float* Wk  = (const float*)d_in[4];
  const float* bk  = (const float*)d_in[5];
  const float* Wv  = (const float*)d_in[6];
  const float* bv  = (const float*)d_in[7];
  const float* Wo  = (const float*)d_in[8];
  const float* bo  = (const float*)d_in[9];
  const float* W1  = (const float*)d_in[10];
  const float* b1  = (const float*)d_in[11];
  const float* W2  = (const float*)d_in[12];
  const float* b2  = (const float*)d_in[13];

  char* ws = (char*)d_ws;
  const size_t MB = 1024 * 1024;
  u16* enc_bf = (u16*)(ws + 0 * MB);   // 2048x1024
  u16* mem_bf = (u16*)(ws + 4 * MB);   // 4096x1024
  u16* Wq_bf  = (u16*)(ws + 12 * MB);  // 1024x1024
  u16* Wk_bf  = (u16*)(ws + 14 * MB);
  u16* Wv_bf  = (u16*)(ws + 16 * MB);
  u16* Wo_bf  = (u16*)(ws + 18 * MB);
  u16* W1_bf  = (u16*)(ws + 20 * MB);  // 4096x2048
  u16* W2_bf  = (u16*)(ws + 36 * MB);  // 1000x4096
  u16* Qb     = (u16*)(ws + 46 * MB);  // 2048x1024
  u16* Kb     = (u16*)(ws + 50 * MB);  // 4096x1024
  u16* Vtb    = (u16*)(ws + 58 * MB);  // 1024x4096 (V^T)
  u16* AO     = (u16*)(ws + 66 * MB);  // 2048x1024
  u16* OUT    = (u16*)(ws + 70 * MB);  // 2048x1024
  u16* Hh     = (u16*)(ws + 74 * MB);  // 2048x4096   -> total 90 MB

  ConvArgs ca;
  const float* srcs[8] = {enc, mem, Wq, Wk, Wv, Wo, W1, W2};
  u16* dsts[8] = {enc_bf, mem_bf, Wq_bf, Wk_bf, Wv_bf, Wo_bf, W1_bf, W2_bf};
  int sizes[8] = {2048 * 1024, 4096 * 1024, 1024 * 1024, 1024 * 1024,
                  1024 * 1024, 1024 * 1024, 4096 * 2048, 1000 * 4096};
  int start = 0;
  for (int i = 0; i < 8; ++i) {
    ca.src[i] = srcs[i]; ca.dst[i] = dsts[i];
    ca.start4[i] = start; start += sizes[i] / 4;
  }
  ca.start4[8] = start;
  convert_all<<<(start + 255) / 256, 256, 0, stream>>>(ca);

  // Q = enc @ Wq^T + bq                       [2048,1024]
  gemm_nt<1, false, true, false><<<dim3(8, 16), 256, 0, stream>>>(
      enc_bf, 1024, Wq_bf, 1024, nullptr, 0, nullptr, 0, 1024, 0, bq, Qb, 1024, 1024);
  // K = mem @ Wk^T + bk                       [4096,1024]
  gemm_nt<1, false, true, false><<<dim3(8, 32), 256, 0, stream>>>(
      mem_bf, 1024, Wk_bf, 1024, nullptr, 0, nullptr, 0, 1024, 0, bk, Kb, 1024, 1024);
  // V^T = Wv @ mem^T + bv (row bias)          [1024,4096]
  gemm_nt<2, false, true, false><<<dim3(32, 8), 256, 0, stream>>>(
      Wv_bf, 1024, mem_bf, 1024, nullptr, 0, nullptr, 0, 1024, 0, bv, Vtb, 4096, 4096);
  // attention + sparsemax                     [2048,1024]
  attn_sparsemax<<<2048, 512, 0, stream>>>(Qb, Kb, Vtb, AO);
  // OUT = AO @ Wo^T + bo                      [2048,1024]
  gemm_nt<1, false, true, false><<<dim3(8, 16), 256, 0, stream>>>(
      AO, 1024, Wo_bf, 1024, nullptr, 0, nullptr, 0, 1024, 0, bo, OUT, 1024, 1024);
  // H = relu(enc@W1a^T + OUT@W1b^T + b1)      [2048,4096]  (concat avoided)
  gemm_nt<1, true, true, true><<<dim3(32, 16), 256, 0, stream>>>(
      enc_bf, 1024, W1_bf, 2048, OUT, 1024, W1_bf + 1024, 2048, 1024, 1024, b1, Hh, 4096, 4096);
  // out = H @ W2^T + b2 (fp32 out, N=1000)    [2048,1000]
  gemm_nt<1, false, false, false><<<dim3(8, 16), 256, 0, stream>>>(
      Hh, 4096, W2_bf, 4096, nullptr, 0, nullptr, 0, 4096, 0, b2, d_out, 1000, 1000);
}